// Round 5
// baseline (344.281 us; speedup 1.0000x reference)
//
#include <hip/hip_runtime.h>
#include <cstdint>
#include <cstddef>

#define BATCH 8192
#define DIN   1025
#define HID   1024
#define NACT  1026
#define NHEAD 513
#define KSEL  32
#define KP0   1088   /* DIN padded to multiple of 64 */
#define NP2   1152   /* NACT padded to multiple of 128 */

typedef unsigned short u16;
typedef short bf16x8 __attribute__((ext_vector_type(8)));
typedef float f32x4 __attribute__((ext_vector_type(4)));

__device__ __forceinline__ u16 f2bf(float f) {
  unsigned u = __float_as_uint(f);
  u += 0x7fff + ((u >> 16) & 1);   // round-to-nearest-even
  return (u16)(u >> 16);
}
__device__ __forceinline__ float bf2f(u16 h) {
  return __uint_as_float((unsigned)h << 16);
}

// ---------------- conversion kernels ----------------

// state f32 [BATCH][DIN] -> bf16 [BATCH][KP0], zero-padded K. 4 elems/thread.
__global__ void cvt_state(const float* __restrict__ in, u16* __restrict__ out) {
  int idx = blockIdx.x * 256 + threadIdx.x;           // one idx = 4 output elems
  const int QPR = KP0 / 4;                            // 272 quads per row
  if (idx >= BATCH * QPR) return;
  int r  = idx / QPR;
  int c4 = (idx - r * QPR) * 4;
  const float* src = in + (size_t)r * DIN + c4;
  ushort4 o;
  if (c4 + 3 < DIN) {
    o.x = f2bf(src[0]); o.y = f2bf(src[1]); o.z = f2bf(src[2]); o.w = f2bf(src[3]);
  } else {
    o.x = (c4 + 0 < DIN) ? f2bf(src[0]) : 0;
    o.y = (c4 + 1 < DIN) ? f2bf(src[1]) : 0;
    o.z = (c4 + 2 < DIN) ? f2bf(src[2]) : 0;
    o.w = (c4 + 3 < DIN) ? f2bf(src[3]) : 0;
  }
  *(ushort4*)(out + (size_t)r * KP0 + c4) = o;
}

// All three weight matrices: f32 [K][N] -> bf16 [Np][Kp] transposed+padded.
__global__ void cvt_w_all(const float* __restrict__ W0, const float* __restrict__ W1,
                          const float* __restrict__ W2,
                          u16* __restrict__ W0t, u16* __restrict__ W1t,
                          u16* __restrict__ W2t) {
  const float* W; u16* Wt; int K, N, Kp, Np;
  if (blockIdx.z == 0)      { W = W0; Wt = W0t; K = DIN; N = HID;  Kp = KP0; Np = HID; }
  else if (blockIdx.z == 1) { W = W1; Wt = W1t; K = HID; N = HID;  Kp = HID; Np = HID; }
  else                      { W = W2; Wt = W2t; K = HID; N = NACT; Kp = HID; Np = NP2; }
  int k0 = blockIdx.y * 32, n0 = blockIdx.x * 32;
  if (k0 >= Kp || n0 >= Np) return;
  __shared__ float tile[32][33];
  int tx = threadIdx.x, ty = threadIdx.y;
#pragma unroll
  for (int i = 0; i < 32; i += 8) {
    int k = k0 + ty + i, n = n0 + tx;
    tile[ty + i][tx] = (k < K && n < N) ? W[(size_t)k * N + n] : 0.f;
  }
  __syncthreads();
#pragma unroll
  for (int i = 0; i < 32; i += 8) {
    int n = n0 + ty + i, k = k0 + tx;
    if (n < Np && k < Kp) Wt[(size_t)n * Kp + k] = f2bf(tile[tx][ty + i]);
  }
}

// ---------------- no-LDS GEMM: C[M][ldc] = A[M][K] * Bt[N][K]^T (+bias, relu) --------
// Block 128x128 (2x2 waves of 64x64). NO LDS, NO barriers: each wave loads its
// MFMA fragments directly global->VGPR (coalesced 16 rows x 64B per load).
// A-tiles and the whole B panel are L2-resident (XCD swizzle groups all NT
// n-tiles of an m-tile on one XCD). With no __syncthreads in the K-loop the
// compiler schedules load<->MFMA with fine-grained vmcnt (no vmcnt(0) drain).
// K is a template constant -> fully unrolled loop, all offsets imm13.

template<bool RELU, bool OBF16, int NT, int K>
__global__ __launch_bounds__(256, 2)
void gemm_direct(const u16* __restrict__ A, const u16* __restrict__ Bt,
                 const float* __restrict__ bias, int nbias,
                 void* __restrict__ Cout, int ldc)
{
  // XCD swizzle: d = group*(8*NT) + n*8 + m8 ; mtile = group*8 + m8
  const int d     = blockIdx.x;
  const int group = d / (8 * NT);
  const int rsub  = d - group * (8 * NT);
  const int ntile = rsub >> 3;
  const int mtile = group * 8 + (rsub & 7);

  const int tid   = threadIdx.x;
  const int wave  = tid >> 6;
  const int lane  = tid & 63;
  const int lr = lane & 15, lq = lane >> 4;
  const size_t bm = (size_t)mtile * 128 + (wave >> 1) * 64;
  const size_t bn = (size_t)ntile * 128 + (wave & 1) * 64;

  // fragment base pointers: A[bm + t*16 + lr][lq*8 ...], Bt[bn + t*16 + lr][lq*8 ...]
  const u16* pa[4]; const u16* pb[4];
#pragma unroll
  for (int t = 0; t < 4; ++t) {
    pa[t] = A  + (bm + t * 16 + lr) * (size_t)K + lq * 8;
    pb[t] = Bt + (bn + t * 16 + lr) * (size_t)K + lq * 8;
  }

  f32x4 acc[4][4] = {};

#pragma unroll
  for (int k0 = 0; k0 < K; k0 += 32) {
    bf16x8 af[4], bf[4];
#pragma unroll
    for (int t = 0; t < 4; ++t) af[t] = *(const bf16x8*)(pa[t] + k0);
#pragma unroll
    for (int t = 0; t < 4; ++t) bf[t] = *(const bf16x8*)(pb[t] + k0);
#pragma unroll
    for (int tm = 0; tm < 4; ++tm)
#pragma unroll
      for (int tn = 0; tn < 4; ++tn)
        acc[tm][tn] = __builtin_amdgcn_mfma_f32_16x16x32_bf16(af[tm], bf[tn], acc[tm][tn], 0, 0, 0);
  }

  // epilogue: D row = lq*4 + r, col = lr (m89-verified layout)
#pragma unroll
  for (int tm = 0; tm < 4; ++tm) {
    size_t rw = bm + tm * 16 + lq * 4;
#pragma unroll
    for (int tn = 0; tn < 4; ++tn) {
      int col = (int)bn + tn * 16 + lr;
      float bv = (col < nbias) ? bias[col] : 0.f;
#pragma unroll
      for (int r = 0; r < 4; ++r) {
        float v = acc[tm][tn][r] + bv;
        if (RELU) v = fmaxf(v, 0.f);
        if (OBF16) ((u16*)Cout)[(rw + r) * ldc + col] = f2bf(v);
        else       ((float*)Cout)[(rw + r) * ldc + col] = v;
      }
    }
  }
}

// ---------------- sampling without replacement ----------------
// one block (2 waves) per batch row: wave 0 -> group R, wave 1 -> group S.
// Incremental: e_i = exp(x_i - m); S = sum e; T = sum e*x.
// step t: logZ = m + log(S_t); ent += logZ - T_t/S_t; logp += x_idx - logZ;
// removals via exclusive lane prefix sums over the 32 steps.

__global__ void sample_k(const u16* __restrict__ logits,
                         const int* __restrict__ idxR, const int* __restrict__ lenR,
                         const int* __restrict__ idxS, const int* __restrict__ lenS,
                         float* __restrict__ out)
{
  const int row  = blockIdx.x;
  const int w    = threadIdx.x >> 6;
  const int lane = threadIdx.x & 63;
  const u16* x = logits + (size_t)row * NP2 + w * NHEAD;
  const int* sidx = (w ? idxS : idxR) + (size_t)row * KSEL;
  const int slen  = (w ? lenS : lenR)[row];

  float m = -3.4e38f;
  for (int i = lane; i < NHEAD; i += 64) m = fmaxf(m, bf2f(x[i]));
#pragma unroll
  for (int d = 32; d; d >>= 1) m = fmaxf(m, __shfl_xor(m, d, 64));

  float S = 0.f, T = 0.f;
  for (int i = lane; i < NHEAD; i += 64) {
    float xi = bf2f(x[i]);
    float e = __expf(xi - m);
    S += e; T += e * xi;
  }
#pragma unroll
  for (int d = 32; d; d >>= 1) { S += __shfl_xor(S, d, 64); T += __shfl_xor(T, d, 64); }

  float e = 0.f, ex = 0.f, xt = 0.f;
  int active = (lane < KSEL) && (lane < slen);
  int valid = 0;
  if (active) {
    int id = sidx[lane];
    if (id >= 0) {
      valid = 1;
      xt = bf2f(x[id]);
      e  = __expf(xt - m);
      ex = e * xt;
    }
  }
  float pe = e, pex = ex;
#pragma unroll
  for (int d = 1; d < 32; d <<= 1) {
    float a = __shfl_up(pe, d, 64);
    float b = __shfl_up(pex, d, 64);
    if (lane >= d) { pe += a; pex += b; }
  }
  float lp = 0.f, en = 0.f;
  if (active) {
    float St = S - (pe - e);
    float Tt = T - (pex - ex);
    float logZ = m + __logf(St);
    en = logZ - Tt / St;
    if (valid) lp = xt - logZ;
  }
#pragma unroll
  for (int d = 32; d; d >>= 1) { lp += __shfl_xor(lp, d, 64); en += __shfl_xor(en, d, 64); }

  __shared__ float sh[4];
  if (lane == 0) { sh[w * 2] = lp; sh[w * 2 + 1] = en; }
  __syncthreads();
  if (threadIdx.x == 0) {
    out[row]         = sh[0] + sh[2];
    out[BATCH + row] = sh[1] + sh[3];
  }
}

// ---------------- launch ----------------

extern "C" void kernel_launch(void* const* d_in, const int* in_sizes, int n_in,
                              void* d_out, int out_size, void* d_ws, size_t ws_size,
                              hipStream_t stream) {
  (void)in_sizes; (void)n_in; (void)out_size; (void)ws_size;
  const float* state = (const float*)d_in[0];
  const float* W0 = (const float*)d_in[1];
  const float* b0 = (const float*)d_in[2];
  const float* W1 = (const float*)d_in[3];
  const float* b1 = (const float*)d_in[4];
  const float* W2 = (const float*)d_in[5];
  const float* b2 = (const float*)d_in[6];
  const int* idxR = (const int*)d_in[7];
  const int* lenR = (const int*)d_in[8];
  const int* idxS = (const int*)d_in[9];
  const int* lenS = (const int*)d_in[10];
  float* out = (float*)d_out;

  char* ws = (char*)d_ws;
  size_t off = 0;
  auto alloc = [&](size_t bytes) -> char* {
    char* p = ws + off;
    off = (off + bytes + 255) & ~(size_t)255;
    return p;
  };
  u16* As     = (u16*)alloc((size_t)BATCH * KP0 * 2);   // 17.8 MB
  u16* W0t    = (u16*)alloc((size_t)HID * KP0 * 2);     //  2.2 MB
  u16* W1t    = (u16*)alloc((size_t)HID * HID * 2);     //  2.1 MB
  u16* W2t    = (u16*)alloc((size_t)NP2 * HID * 2);     //  2.4 MB
  u16* h1     = (u16*)alloc((size_t)BATCH * HID * 2);   // 16.8 MB
  u16* lgts   = (u16*)alloc((size_t)BATCH * NP2 * 2);   // 18.9 MB
  u16* h2 = As;   // As is dead after GEMM1; reuse for h2

  cvt_state<<<(BATCH * (KP0 / 4) + 255) / 256, 256, 0, stream>>>(state, As);
  cvt_w_all<<<dim3(NP2 / 32, KP0 / 32, 3), dim3(32, 8), 0, stream>>>(W0, W1, W2, W0t, W1t, W2t);

  gemm_direct<true,  true, 8, KP0><<<(BATCH / 128) * (HID / 128) , 256, 0, stream>>>(As, W0t, b0, HID,  h1,   HID);
  gemm_direct<true,  true, 8, HID><<<(BATCH / 128) * (HID / 128) , 256, 0, stream>>>(h1, W1t, b1, HID,  h2,   HID);
  gemm_direct<false, true, 9, HID><<<(BATCH / 128) * (NP2 / 128) , 256, 0, stream>>>(h2, W2t, b2, NACT, lgts, NP2);

  sample_k<<<BATCH, 128, 0, stream>>>(lgts, idxR, lenR, idxS, lenS, out);
}

// Round 6
// 225.880 us; speedup vs baseline: 1.5242x; 1.5242x over previous
//
#include <hip/hip_runtime.h>
#include <cstdint>
#include <cstddef>

#define BATCH 8192
#define DIN   1025
#define HID   1024
#define NACT  1026
#define NHEAD 513
#define KSEL  32
#define KP0   1088   /* DIN padded to multiple of 64 */
#define NP2   1152   /* NACT padded to multiple of 128 */

typedef unsigned short u16;
typedef short bf16x8 __attribute__((ext_vector_type(8)));
typedef float f32x4 __attribute__((ext_vector_type(4)));

__device__ __forceinline__ u16 f2bf(float f) {
  unsigned u = __float_as_uint(f);
  u += 0x7fff + ((u >> 16) & 1);   // round-to-nearest-even
  return (u16)(u >> 16);
}
__device__ __forceinline__ float bf2f(u16 h) {
  return __uint_as_float((unsigned)h << 16);
}

__device__ __forceinline__ void async_cp16(const u16* g, u16* l) {
  __builtin_amdgcn_global_load_lds((const __attribute__((address_space(1))) void*)g,
                                   (__attribute__((address_space(3))) void*)l,
                                   16, 0, 0);
}

// ---------------- fused conversion kernel ----------------
// blocks [0, 8704): state f32 [BATCH][DIN] -> bf16 [BATCH][KP0] (4 elems/thread)
// blocks [8704, 11968): W0/W1/W2 f32 [K][N] -> bf16 [Np][Kp] transposed+padded

__global__ void cvt_all(const float* __restrict__ state,
                        const float* __restrict__ W0, const float* __restrict__ W1,
                        const float* __restrict__ W2,
                        u16* __restrict__ As, u16* __restrict__ W0t,
                        u16* __restrict__ W1t, u16* __restrict__ W2t) {
  const int b = blockIdx.x;
  const int tid = threadIdx.x;
  if (b < 8704) {
    int idx = b * 256 + tid;                 // one idx = 4 output elems
    const int QPR = KP0 / 4;                 // 272 quads per row
    int r  = idx / QPR;
    int c4 = (idx - r * QPR) * 4;
    const float* src = state + (size_t)r * DIN + c4;
    ushort4 o;
    if (c4 + 3 < DIN) {
      o.x = f2bf(src[0]); o.y = f2bf(src[1]); o.z = f2bf(src[2]); o.w = f2bf(src[3]);
    } else {
      o.x = (c4 + 0 < DIN) ? f2bf(src[0]) : 0;
      o.y = (c4 + 1 < DIN) ? f2bf(src[1]) : 0;
      o.z = (c4 + 2 < DIN) ? f2bf(src[2]) : 0;
      o.w = (c4 + 3 < DIN) ? f2bf(src[3]) : 0;
    }
    *(ushort4*)(As + (size_t)r * KP0 + c4) = o;
    return;
  }
  int w = b - 8704;
  const float* W; u16* Wt; int K, N, Kp, Np, nx;
  if (w < 1088)      { W = W0; Wt = W0t; K = DIN; N = HID;  Kp = KP0; Np = HID; nx = 32; }
  else if (w < 2112) { w -= 1088; W = W1; Wt = W1t; K = HID; N = HID;  Kp = HID; Np = HID; nx = 32; }
  else               { w -= 2112; W = W2; Wt = W2t; K = HID; N = NACT; Kp = HID; Np = NP2; nx = 36; }
  int n0 = (w % nx) * 32, k0 = (w / nx) * 32;
  __shared__ float tile[32][33];
  int tx = tid & 31, ty = tid >> 5;
#pragma unroll
  for (int i = 0; i < 32; i += 8) {
    int k = k0 + ty + i, n = n0 + tx;
    tile[ty + i][tx] = (k < K && n < N) ? W[(size_t)k * N + n] : 0.f;
  }
  __syncthreads();
#pragma unroll
  for (int i = 0; i < 32; i += 8) {
    int n = n0 + ty + i, k = k0 + tx;
    if (n < Np && k < Kp) Wt[(size_t)n * Kp + k] = f2bf(tile[tx][ty + i]);
  }
}

// -------- wave-autonomous GEMM: C[M][ldc] = A[M][K]*Bt[N][K]^T (+bias,relu) --------
// Block 256 = 4 waves arranged 2x2; each wave independently computes a 64x64 tile
// from its PRIVATE double-buffered LDS (2 x (4KB A + 4KB B)). NO __syncthreads:
// per-wave global_load_lds prefetch one iter ahead + asm s_waitcnt vmcnt(8) gives
// the AITER-style fine-grained pipeline (loads stay in flight during MFMA).
// XCD swizzle keeps A-tiles + B panel L2-resident per XCD.
// LDS bank swizzle (BK=32, row=64B): chunk c of row r stored at slot c^((r>>1)&3)
// -> staging dst stays lane-contiguous, fragment ds_read_b128 is 2-way only (free).

template<bool RELU, bool OBF16, int NT, int K>
__global__ __launch_bounds__(256, 2)
void gemm_wa(const u16* __restrict__ A, const u16* __restrict__ Bt,
             const float* __restrict__ bias, int nbias,
             void* __restrict__ Cout, int ldc)
{
  __shared__ __align__(16) u16 lds[32768];   // 64 KB = 4 waves x 16 KB

  // XCD swizzle: d = group*(8*NT) + n*8 + m8 ; mtile = group*8 + m8
  const int d     = blockIdx.x;
  const int group = d / (8 * NT);
  const int rsub  = d - group * (8 * NT);
  const int ntile = rsub >> 3;
  const int mtile = group * 8 + (rsub & 7);

  const int tid  = threadIdx.x;
  const int wave = tid >> 6;
  const int lane = tid & 63;
  const int lr = lane & 15, lq = lane >> 4;

  const size_t bm = (size_t)mtile * 128 + (wave >> 1) * 64;
  const size_t bn = (size_t)ntile * 128 + (wave & 1) * 64;

  // staging source: load j covers rows j*16+(lane>>2); lane reads global chunk
  // g = (lane&3) ^ ((lane>>3)&3) of that row (XOR-swizzle permutation within 64B)
  const int srow = lane >> 2;
  const int g    = (lane & 3) ^ ((lane >> 3) & 3);
  const u16* gA = A  + (bm + srow) * (size_t)K + g * 8;
  const u16* gB = Bt + (bn + srow) * (size_t)K + g * 8;

  u16* wlds = lds + wave * 8192;   // 16 KB private: buf b at +b*4096 (A), +b*4096+2048 (B)

  f32x4 acc[4][4] = {};

  // fragment read: element (tm*16+lr, lq*8..) at slot s = lq ^ ((lr>>1)&3)
  const int s = lq ^ ((lr >> 1) & 3);
  const int foff = lr * 32 + s * 8;

  auto issue = [&](int k0, int b) {
    u16* la = wlds + b * 4096;
    u16* lb = la + 2048;
#pragma unroll
    for (int j = 0; j < 4; ++j)
      async_cp16(gA + k0 + j * 16 * (size_t)K, la + j * 512);
#pragma unroll
    for (int j = 0; j < 4; ++j)
      async_cp16(gB + k0 + j * 16 * (size_t)K, lb + j * 512);
  };

  auto compute = [&](int b) {
    const u16* la = wlds + b * 4096 + foff;
    const u16* lb = la + 2048;
    bf16x8 af[4], bf[4];
#pragma unroll
    for (int t = 0; t < 4; ++t) af[t] = *(const bf16x8*)(la + t * 512);
#pragma unroll
    for (int t = 0; t < 4; ++t) bf[t] = *(const bf16x8*)(lb + t * 512);
#pragma unroll
    for (int tm = 0; tm < 4; ++tm)
#pragma unroll
      for (int tn = 0; tn < 4; ++tn)
        acc[tm][tn] = __builtin_amdgcn_mfma_f32_16x16x32_bf16(af[tm], bf[tn], acc[tm][tn], 0, 0, 0);
  };

  issue(0, 0);
  int b = 0;
  for (int k0 = 0; k0 < K - 32; k0 += 32) {
    issue(k0 + 32, b ^ 1);
    // 16 outstanding: wait until the 8 older (this iter's) have landed in LDS
    asm volatile("s_waitcnt vmcnt(8)" ::: "memory");
    compute(b);
    b ^= 1;
  }
  asm volatile("s_waitcnt vmcnt(0)" ::: "memory");
  compute(b);

  // epilogue: D row = lq*4 + r, col = lr (m89-verified layout)
#pragma unroll
  for (int tm = 0; tm < 4; ++tm) {
    size_t rw = bm + tm * 16 + lq * 4;
#pragma unroll
    for (int tn = 0; tn < 4; ++tn) {
      int col = (int)bn + tn * 16 + lr;
      float bv = (col < nbias) ? bias[col] : 0.f;
#pragma unroll
      for (int r = 0; r < 4; ++r) {
        float v = acc[tm][tn][r] + bv;
        if (RELU) v = fmaxf(v, 0.f);
        if (OBF16) ((u16*)Cout)[(rw + r) * ldc + col] = f2bf(v);
        else       ((float*)Cout)[(rw + r) * ldc + col] = v;
      }
    }
  }
}

// ---------------- sampling without replacement ----------------
// one block (2 waves) per batch row: wave 0 -> group R, wave 1 -> group S.
// Incremental: e_i = exp(x_i - m); S = sum e; T = sum e*x.
// step t: logZ = m + log(S_t); ent += logZ - T_t/S_t; logp += x_idx - logZ;
// removals via exclusive lane prefix sums over the 32 steps.

__global__ void sample_k(const u16* __restrict__ logits,
                         const int* __restrict__ idxR, const int* __restrict__ lenR,
                         const int* __restrict__ idxS, const int* __restrict__ lenS,
                         float* __restrict__ out)
{
  const int row  = blockIdx.x;
  const int w    = threadIdx.x >> 6;
  const int lane = threadIdx.x & 63;
  const u16* x = logits + (size_t)row * NP2 + w * NHEAD;
  const int* sidx = (w ? idxS : idxR) + (size_t)row * KSEL;
  const int slen  = (w ? lenS : lenR)[row];

  float m = -3.4e38f;
  for (int i = lane; i < NHEAD; i += 64) m = fmaxf(m, bf2f(x[i]));
#pragma unroll
  for (int d = 32; d; d >>= 1) m = fmaxf(m, __shfl_xor(m, d, 64));

  float S = 0.f, T = 0.f;
  for (int i = lane; i < NHEAD; i += 64) {
    float xi = bf2f(x[i]);
    float e = __expf(xi - m);
    S += e; T += e * xi;
  }
#pragma unroll
  for (int d = 32; d; d >>= 1) { S += __shfl_xor(S, d, 64); T += __shfl_xor(T, d, 64); }

  float e = 0.f, ex = 0.f, xt = 0.f;
  int active = (lane < KSEL) && (lane < slen);
  int valid = 0;
  if (active) {
    int id = sidx[lane];
    if (id >= 0) {
      valid = 1;
      xt = bf2f(x[id]);
      e  = __expf(xt - m);
      ex = e * xt;
    }
  }
  float pe = e, pex = ex;
#pragma unroll
  for (int d = 1; d < 32; d <<= 1) {
    float a = __shfl_up(pe, d, 64);
    float b = __shfl_up(pex, d, 64);
    if (lane >= d) { pe += a; pex += b; }
  }
  float lp = 0.f, en = 0.f;
  if (active) {
    float St = S - (pe - e);
    float Tt = T - (pex - ex);
    float logZ = m + __logf(St);
    en = logZ - Tt / St;
    if (valid) lp = xt - logZ;
  }
#pragma unroll
  for (int d = 32; d; d >>= 1) { lp += __shfl_xor(lp, d, 64); en += __shfl_xor(en, d, 64); }

  __shared__ float sh[4];
  if (lane == 0) { sh[w * 2] = lp; sh[w * 2 + 1] = en; }
  __syncthreads();
  if (threadIdx.x == 0) {
    out[row]         = sh[0] + sh[2];
    out[BATCH + row] = sh[1] + sh[3];
  }
}

// ---------------- launch ----------------

extern "C" void kernel_launch(void* const* d_in, const int* in_sizes, int n_in,
                              void* d_out, int out_size, void* d_ws, size_t ws_size,
                              hipStream_t stream) {
  (void)in_sizes; (void)n_in; (void)out_size; (void)ws_size;
  const float* state = (const float*)d_in[0];
  const float* W0 = (const float*)d_in[1];
  const float* b0 = (const float*)d_in[2];
  const float* W1 = (const float*)d_in[3];
  const float* b1 = (const float*)d_in[4];
  const float* W2 = (const float*)d_in[5];
  const float* b2 = (const float*)d_in[6];
  const int* idxR = (const int*)d_in[7];
  const int* lenR = (const int*)d_in[8];
  const int* idxS = (const int*)d_in[9];
  const int* lenS = (const int*)d_in[10];
  float* out = (float*)d_out;

  char* ws = (char*)d_ws;
  size_t off = 0;
  auto alloc = [&](size_t bytes) -> char* {
    char* p = ws + off;
    off = (off + bytes + 255) & ~(size_t)255;
    return p;
  };
  u16* As     = (u16*)alloc((size_t)BATCH * KP0 * 2);   // 17.8 MB
  u16* W0t    = (u16*)alloc((size_t)HID * KP0 * 2);     //  2.2 MB
  u16* W1t    = (u16*)alloc((size_t)HID * HID * 2);     //  2.1 MB
  u16* W2t    = (u16*)alloc((size_t)NP2 * HID * 2);     //  2.4 MB
  u16* h1     = (u16*)alloc((size_t)BATCH * HID * 2);   // 16.8 MB
  u16* lgts   = (u16*)alloc((size_t)BATCH * NP2 * 2);   // 18.9 MB
  u16* h2 = As;   // As is dead after GEMM1; reuse for h2

  cvt_all<<<8704 + 3264, 256, 0, stream>>>(state, W0, W1, W2, As, W0t, W1t, W2t);

  gemm_wa<true,  true, 8, KP0><<<(BATCH / 128) * (HID / 128), 256, 0, stream>>>(As, W0t, b0, HID,  h1,   HID);
  gemm_wa<true,  true, 8, HID><<<(BATCH / 128) * (HID / 128), 256, 0, stream>>>(h1, W1t, b1, HID,  h2,   HID);
  gemm_wa<false, true, 9, HID><<<(BATCH / 128) * (NP2 / 128), 256, 0, stream>>>(h2, W2t, b2, NACT, lgts, NP2);

  sample_k<<<BATCH, 128, 0, stream>>>(lgts, idxR, lenR, idxS, lenS, out);
}

// Round 7
// 202.345 us; speedup vs baseline: 1.7015x; 1.1163x over previous
//
#include <hip/hip_runtime.h>
#include <cstdint>
#include <cstddef>

#define BATCH 8192
#define DIN   1025
#define HID   1024
#define NACT  1026
#define NHEAD 513
#define KSEL  32
#define KP0   1088   /* DIN padded to multiple of 64 */
#define NP2   1152   /* NACT padded to multiple of 128 */

typedef unsigned short u16;
typedef short bf16x8 __attribute__((ext_vector_type(8)));
typedef float f32x4 __attribute__((ext_vector_type(4)));

__device__ __forceinline__ u16 f2bf(float f) {
  unsigned u = __float_as_uint(f);
  u += 0x7fff + ((u >> 16) & 1);   // round-to-nearest-even
  return (u16)(u >> 16);
}
__device__ __forceinline__ float bf2f(u16 h) {
  return __uint_as_float((unsigned)h << 16);
}

__device__ __forceinline__ void async_cp16(const u16* g, u16* l) {
  __builtin_amdgcn_global_load_lds((const __attribute__((address_space(1))) void*)g,
                                   (__attribute__((address_space(3))) void*)l,
                                   16, 0, 0);
}

// ---------------- fused conversion kernel ----------------
// blocks [0, 8704): state f32 [BATCH][DIN] -> bf16 [BATCH][KP0] (4 elems/thread)
// blocks [8704, 11968): W0/W1/W2 f32 [K][N] -> bf16 [Np][Kp] transposed+padded

__global__ void cvt_all(const float* __restrict__ state,
                        const float* __restrict__ W0, const float* __restrict__ W1,
                        const float* __restrict__ W2,
                        u16* __restrict__ As, u16* __restrict__ W0t,
                        u16* __restrict__ W1t, u16* __restrict__ W2t) {
  const int b = blockIdx.x;
  const int tid = threadIdx.x;
  if (b < 8704) {
    int idx = b * 256 + tid;                 // one idx = 4 output elems
    const int QPR = KP0 / 4;                 // 272 quads per row
    int r  = idx / QPR;
    int c4 = (idx - r * QPR) * 4;
    const float* src = state + (size_t)r * DIN + c4;
    ushort4 o;
    if (c4 + 3 < DIN) {
      o.x = f2bf(src[0]); o.y = f2bf(src[1]); o.z = f2bf(src[2]); o.w = f2bf(src[3]);
    } else {
      o.x = (c4 + 0 < DIN) ? f2bf(src[0]) : 0;
      o.y = (c4 + 1 < DIN) ? f2bf(src[1]) : 0;
      o.z = (c4 + 2 < DIN) ? f2bf(src[2]) : 0;
      o.w = (c4 + 3 < DIN) ? f2bf(src[3]) : 0;
    }
    *(ushort4*)(As + (size_t)r * KP0 + c4) = o;
    return;
  }
  int w = b - 8704;
  const float* W; u16* Wt; int K, N, Kp, Np, nx;
  if (w < 1088)      { W = W0; Wt = W0t; K = DIN; N = HID;  Kp = KP0; Np = HID; nx = 32; }
  else if (w < 2112) { w -= 1088; W = W1; Wt = W1t; K = HID; N = HID;  Kp = HID; Np = HID; nx = 32; }
  else               { w -= 2112; W = W2; Wt = W2t; K = HID; N = NACT; Kp = HID; Np = NP2; nx = 36; }
  int n0 = (w % nx) * 32, k0 = (w / nx) * 32;
  __shared__ float tile[32][33];
  int tx = tid & 31, ty = tid >> 5;
#pragma unroll
  for (int i = 0; i < 32; i += 8) {
    int k = k0 + ty + i, n = n0 + tx;
    tile[ty + i][tx] = (k < K && n < N) ? W[(size_t)k * N + n] : 0.f;
  }
  __syncthreads();
#pragma unroll
  for (int i = 0; i < 32; i += 8) {
    int n = n0 + ty + i, k = k0 + tx;
    if (n < Np && k < Kp) Wt[(size_t)n * Kp + k] = f2bf(tile[tx][ty + i]);
  }
}

// ---- m97-structure GEMM + dbuf + RAW-barrier pipeline ---------------------------
// C[M][ldc] = A[M][K]*Bt[N][K]^T (+bias, relu). Block 128x128, BK=32, 4 waves of
// 64x64 (4x4 MFMA 16x16x32). Block-shared staging (A 8KB + B 8KB per iter, 4
// global_load_lds_dwordx4 per thread). Double-buffered LDS (2x16KB). The K-loop
// uses RAW `s_barrier` + manual `s_waitcnt vmcnt(4)`: next-iter's 4 staging loads
// stay IN FLIGHT across the barrier (no __syncthreads vmcnt(0) drain). No other
// vmem ops in the loop body, launch_bounds(256,2) -> no spills, so the vmcnt
// arithmetic is exact. XCD swizzle for L2 residency; XOR bank swizzle keeps
// ds_read_b128 at <=2-way (free) while global_load_lds dst stays lane-contiguous.

template<bool RELU, int NT, int K>
__global__ __launch_bounds__(256, 2)
void gemm_bt(const u16* __restrict__ A, const u16* __restrict__ Bt,
             const float* __restrict__ bias, int nbias,
             u16* __restrict__ Cout, int ldc)
{
  __shared__ __align__(16) u16 lds[16384];   // 2 bufs x (A 4096 + B 4096 u16) = 32 KB

  // XCD swizzle: d = group*(8*NT) + n*8 + m8 ; mtile = group*8 + m8
  const int d     = blockIdx.x;
  const int group = d / (8 * NT);
  const int rsub  = d - group * (8 * NT);
  const int ntile = rsub >> 3;
  const int mtile = group * 8 + (rsub & 7);

  const int tid  = threadIdx.x;
  const int wave = tid >> 6;
  const int lane = tid & 63;
  const int waveM = wave >> 1, waveN = wave & 1;
  const int lr = lane & 15, lq = lane >> 4;
  const size_t bm = (size_t)mtile * 128;
  const size_t bn = (size_t)ntile * 128;

  // staging: tile = 512 chunks of 16B; chunk c -> row c>>2, slot c&3 (linear in LDS);
  // data = global kchunk g = (c&3) ^ ((row>>1)&3). Thread covers c0 = wave*64+lane
  // (inst 0) and c1 = c0+256 (inst 1) for each of A and B.
  const int c0   = wave * 64 + lane;
  const int row0 = c0 >> 2;                     // 0..63
  const int g0   = (c0 & 3) ^ ((row0 >> 1) & 3);
  const int c1   = c0 + 256;
  const int row1 = c1 >> 2;                     // 64..127
  const int g1   = (c1 & 3) ^ ((row1 >> 1) & 3);
  const u16* gA0 = A  + (bm + row0) * (size_t)K + g0 * 8;
  const u16* gA1 = A  + (bm + row1) * (size_t)K + g1 * 8;
  const u16* gB0 = Bt + (bn + row0) * (size_t)K + g0 * 8;
  const u16* gB1 = Bt + (bn + row1) * (size_t)K + g1 * 8;
  u16* lA = lds + wave * 512;          // +buf*8192; inst1 at +2048
  u16* lB = lds + 4096 + wave * 512;

  f32x4 acc[4][4] = {};

  // fragment: element (row, lq*8..) at slot s = lq ^ ((lr>>1)&3); addr row*32 + s*8
  const int s = lq ^ ((lr >> 1) & 3);
  const u16* pa = lds + (waveM * 64 + lr) * 32 + s * 8;
  const u16* pb = lds + 4096 + (waveN * 64 + lr) * 32 + s * 8;

  auto issue = [&](int k0, int b) {
    u16* a  = lA + b * 8192;
    u16* bb = lB + b * 8192;
    async_cp16(gA0 + k0, a);
    async_cp16(gA1 + k0, a + 2048);
    async_cp16(gB0 + k0, bb);
    async_cp16(gB1 + k0, bb + 2048);
  };

  const int NIT = K / 32;
  issue(0, 0);
#pragma unroll 2
  for (int it = 0; it < NIT; ++it) {
    const int b = it & 1;
    if (it + 1 < NIT) {
      issue((it + 1) * 32, b ^ 1);
      // 8 outstanding; wait until only the 4 newest remain -> buf b fully staged
      asm volatile("s_waitcnt vmcnt(4)\n\ts_barrier" ::: "memory");
    } else {
      asm volatile("s_waitcnt vmcnt(0)\n\ts_barrier" ::: "memory");
    }

    bf16x8 af[4], bf[4];
    const u16* qa = pa + b * 8192;
    const u16* qb = pb + b * 8192;
#pragma unroll
    for (int t = 0; t < 4; ++t) {
      af[t] = *(const bf16x8*)(qa + t * 512);   // +16 rows * 32 stride
      bf[t] = *(const bf16x8*)(qb + t * 512);
    }
#pragma unroll
    for (int tm = 0; tm < 4; ++tm)
#pragma unroll
      for (int tn = 0; tn < 4; ++tn)
        acc[tm][tn] = __builtin_amdgcn_mfma_f32_16x16x32_bf16(af[tm], bf[tn], acc[tm][tn], 0, 0, 0);

    // all my ds_reads retired (lgkm) -> after barrier, buf b is safe to overwrite
    asm volatile("s_waitcnt lgkmcnt(0)\n\ts_barrier" ::: "memory");
  }

  // epilogue: D row = lq*4 + r, col = lr (m89-verified layout)
#pragma unroll
  for (int tm = 0; tm < 4; ++tm) {
    size_t rw = bm + waveM * 64 + tm * 16 + lq * 4;
#pragma unroll
    for (int tn = 0; tn < 4; ++tn) {
      int col = (int)bn + waveN * 64 + tn * 16 + lr;
      float bv = (col < nbias) ? bias[col] : 0.f;
#pragma unroll
      for (int r = 0; r < 4; ++r) {
        float v = acc[tm][tn][r] + bv;
        if (RELU) v = fmaxf(v, 0.f);
        Cout[(rw + r) * ldc + col] = f2bf(v);
      }
    }
  }
}

// ---------------- sampling without replacement ----------------
// one block (2 waves) per batch row: wave 0 -> group R, wave 1 -> group S.
// Incremental: e_i = exp(x_i - m); S = sum e; T = sum e*x.
// step t: logZ = m + log(S_t); ent += logZ - T_t/S_t; logp += x_idx - logZ;
// removals via exclusive lane prefix sums over the 32 steps.

__global__ void sample_k(const u16* __restrict__ logits,
                         const int* __restrict__ idxR, const int* __restrict__ lenR,
                         const int* __restrict__ idxS, const int* __restrict__ lenS,
                         float* __restrict__ out)
{
  const int row  = blockIdx.x;
  const int w    = threadIdx.x >> 6;
  const int lane = threadIdx.x & 63;
  const u16* x = logits + (size_t)row * NP2 + w * NHEAD;
  const int* sidx = (w ? idxS : idxR) + (size_t)row * KSEL;
  const int slen  = (w ? lenS : lenR)[row];

  float m = -3.4e38f;
  for (int i = lane; i < NHEAD; i += 64) m = fmaxf(m, bf2f(x[i]));
#pragma unroll
  for (int d = 32; d; d >>= 1) m = fmaxf(m, __shfl_xor(m, d, 64));

  float S = 0.f, T = 0.f;
  for (int i = lane; i < NHEAD; i += 64) {
    float xi = bf2f(x[i]);
    float e = __expf(xi - m);
    S += e; T += e * xi;
  }
#pragma unroll
  for (int d = 32; d; d >>= 1) { S += __shfl_xor(S, d, 64); T += __shfl_xor(T, d, 64); }

  float e = 0.f, ex = 0.f, xt = 0.f;
  int active = (lane < KSEL) && (lane < slen);
  int valid = 0;
  if (active) {
    int id = sidx[lane];
    if (id >= 0) {
      valid = 1;
      xt = bf2f(x[id]);
      e  = __expf(xt - m);
      ex = e * xt;
    }
  }
  float pe = e, pex = ex;
#pragma unroll
  for (int d = 1; d < 32; d <<= 1) {
    float a = __shfl_up(pe, d, 64);
    float b = __shfl_up(pex, d, 64);
    if (lane >= d) { pe += a; pex += b; }
  }
  float lp = 0.f, en = 0.f;
  if (active) {
    float St = S - (pe - e);
    float Tt = T - (pex - ex);
    float logZ = m + __logf(St);
    en = logZ - Tt / St;
    if (valid) lp = xt - logZ;
  }
#pragma unroll
  for (int d = 32; d; d >>= 1) { lp += __shfl_xor(lp, d, 64); en += __shfl_xor(en, d, 64); }

  __shared__ float sh[4];
  if (lane == 0) { sh[w * 2] = lp; sh[w * 2 + 1] = en; }
  __syncthreads();
  if (threadIdx.x == 0) {
    out[row]         = sh[0] + sh[2];
    out[BATCH + row] = sh[1] + sh[3];
  }
}

// ---------------- launch ----------------

extern "C" void kernel_launch(void* const* d_in, const int* in_sizes, int n_in,
                              void* d_out, int out_size, void* d_ws, size_t ws_size,
                              hipStream_t stream) {
  (void)in_sizes; (void)n_in; (void)out_size; (void)ws_size;
  const float* state = (const float*)d_in[0];
  const float* W0 = (const float*)d_in[1];
  const float* b0 = (const float*)d_in[2];
  const float* W1 = (const float*)d_in[3];
  const float* b1 = (const float*)d_in[4];
  const float* W2 = (const float*)d_in[5];
  const float* b2 = (const float*)d_in[6];
  const int* idxR = (const int*)d_in[7];
  const int* lenR = (const int*)d_in[8];
  const int* idxS = (const int*)d_in[9];
  const int* lenS = (const int*)d_in[10];
  float* out = (float*)d_out;

  char* ws = (char*)d_ws;
  size_t off = 0;
  auto alloc = [&](size_t bytes) -> char* {
    char* p = ws + off;
    off = (off + bytes + 255) & ~(size_t)255;
    return p;
  };
  u16* As     = (u16*)alloc((size_t)BATCH * KP0 * 2);   // 17.8 MB
  u16* W0t    = (u16*)alloc((size_t)HID * KP0 * 2);     //  2.2 MB
  u16* W1t    = (u16*)alloc((size_t)HID * HID * 2);     //  2.1 MB
  u16* W2t    = (u16*)alloc((size_t)NP2 * HID * 2);     //  2.4 MB
  u16* h1     = (u16*)alloc((size_t)BATCH * HID * 2);   // 16.8 MB
  u16* lgts   = (u16*)alloc((size_t)BATCH * NP2 * 2);   // 18.9 MB
  u16* h2 = As;   // As is dead after GEMM1; reuse for h2

  cvt_all<<<8704 + 3264, 256, 0, stream>>>(state, W0, W1, W2, As, W0t, W1t, W2t);

  gemm_bt<true,  8, KP0><<<(BATCH / 128) * (HID / 128), 256, 0, stream>>>(As, W0t, b0, HID,  h1,   HID);
  gemm_bt<true,  8, HID><<<(BATCH / 128) * (HID / 128), 256, 0, stream>>>(h1, W1t, b1, HID,  h2,   HID);
  gemm_bt<false, 9, HID><<<(BATCH / 128) * (NP2 / 128), 256, 0, stream>>>(h2, W2t, b2, NACT, lgts, NP2);

  sample_k<<<BATCH, 128, 0, stream>>>(lgts, idxR, lenR, idxS, lenS, out);
}